// Round 3
// baseline (45.147 us; speedup 1.0000x reference)
//
#include <hip/hip_runtime.h>
#include <hip/hip_cooperative_groups.h>

namespace cg = cooperative_groups;

// Problem constants (from reference)
#define NTRAJ 64
#define TSTEP 64
#define DFEAT 256
#define NT    (NTRAJ * TSTEP)   // 4096
#define MROWS (2 * NT)          // 8192

// Derived mask sums (exact integers):
//   sum(pos_w) = 64 * 128^2 - 8192        = 1,040,384
//   sum(neg_w) = 8192^2 - 64 * 128^2      = 66,060,288
#define POS_DEN 1040384.0
#define NEG_DEN 66060288.0

// Identity: positive_mask = 1 - tm + eye (done cancels: dm carries a tm
// factor, so (1-dm)(1-tm) == (1-tm)). With zn = row-normalized z:
//   pos_sum = sum_g |S_g|^2 - sum_i |zn_i|^2
//   neg_sum = |sum_i zn_i|^2 - sum_g |S_g|^2
// Group g (0..63) rows: [g*64, g*64+64) and [4096+g*64, 4096+g*64+64).
//
// Single cooperative kernel, 256 blocks x 512 threads (1 block/CU, 8 waves).
// Phase 1: block b normalizes rows [32b, 32b+32) and writes a 256-float
//          partial sum-vector P[b][:] plus diag partial Dp[b].
// grid.sync()
// Phase 2: block 0 folds the 256 partials (group g = blocks
//          {2g, 2g+1, 128+2g, 129+2g}) into the two output scalars.
__global__ __launch_bounds__(512)
void tsl_fused_kernel(const float* __restrict__ z,
                      float* __restrict__ P,    // [256][256]
                      float* __restrict__ Dp,   // [256]
                      float* __restrict__ out)  // [2]
{
    const int b    = blockIdx.x;     // 0..255
    const int tid  = threadIdx.x;    // 0..511
    const int w    = tid >> 6;       // wave 0..7
    const int lane = tid & 63;       // 0..63

    __shared__ float  S[8][256];
    __shared__ float  dd[8];
    __shared__ double W[3][4];

    // ---------------- phase 1 ----------------
    float a0 = 0.f, a1 = 0.f, a2 = 0.f, a3 = 0.f;
    float dpart = 0.f;

    #pragma unroll
    for (int r = 0; r < 4; ++r) {
        const int row = b * 32 + w * 4 + r;
        const float4 v = *reinterpret_cast<const float4*>(
            z + (size_t)row * DFEAT + (size_t)lane * 4);

        float ss = v.x * v.x + v.y * v.y + v.z * v.z + v.w * v.w;
        #pragma unroll
        for (int off = 32; off > 0; off >>= 1)
            ss += __shfl_xor(ss, off, 64);

        const float rinv = 1.0f / fmaxf(sqrtf(ss), 1e-8f);
        a0 += v.x * rinv;
        a1 += v.y * rinv;
        a2 += v.z * rinv;
        a3 += v.w * rinv;
        if (lane == 0) dpart += ss * rinv * rinv;   // |zn_row|^2
    }

    *reinterpret_cast<float4*>(&S[w][lane * 4]) = make_float4(a0, a1, a2, a3);
    if (lane == 0) dd[w] = dpart;
    __syncthreads();

    if (tid < 256) {
        float s = 0.f;
        #pragma unroll
        for (int k = 0; k < 8; ++k) s += S[k][tid];
        P[b * 256 + tid] = s;
        if (tid == 0) {
            float d = 0.f;
            #pragma unroll
            for (int k = 0; k < 8; ++k) d += dd[k];
            Dp[b] = d;
        }
    }

    // ---------------- grid-wide barrier ----------------
    cg::this_grid().sync();

    // ---------------- phase 2 (block 0 only) ----------------
    if (b != 0) return;

    if (tid < 256) {
        double g1 = 0.0, col = 0.0;
        #pragma unroll 8
        for (int g = 0; g < 64; ++g) {
            const float s = P[(2 * g) * 256 + tid] + P[(2 * g + 1) * 256 + tid] +
                            P[(128 + 2 * g) * 256 + tid] + P[(129 + 2 * g) * 256 + tid];
            g1  += (double)s * (double)s;
            col += (double)s;
        }
        double g2 = col * col;
        double dg = (double)Dp[tid];

        #pragma unroll
        for (int off = 32; off > 0; off >>= 1) {
            g1 += __shfl_down(g1, off, 64);
            g2 += __shfl_down(g2, off, 64);
            dg += __shfl_down(dg, off, 64);
        }
        if (lane == 0) { W[0][w] = g1; W[1][w] = g2; W[2][w] = dg; }
    }
    __syncthreads();

    if (tid == 0) {
        const double G1 = W[0][0] + W[0][1] + W[0][2] + W[0][3];
        const double G2 = W[1][0] + W[1][1] + W[1][2] + W[1][3];
        const double DG = W[2][0] + W[2][1] + W[2][2] + W[2][3];
        out[0] = (float)((G1 - DG) / POS_DEN);   // positive_sim
        out[1] = (float)((G2 - G1) / NEG_DEN);   // negative_sim
    }
}

extern "C" void kernel_launch(void* const* d_in, const int* in_sizes, int n_in,
                              void* d_out, int out_size, void* d_ws, size_t ws_size,
                              hipStream_t stream) {
    const float* z = (const float*)d_in[0];
    // d_in[1] (done) provably unused: (1-dm)(1-tm) == (1-tm).
    float* P   = (float*)d_ws;                                      // 256*256 floats
    float* Dp  = (float*)((char*)d_ws + 256 * 256 * sizeof(float)); // 256 floats
    float* out = (float*)d_out;

    void* args[] = { (void*)&z, (void*)&P, (void*)&Dp, (void*)&out };
    hipLaunchCooperativeKernel((const void*)tsl_fused_kernel,
                               dim3(256), dim3(512), args, 0, stream);
}

// Round 4
// 20.217 us; speedup vs baseline: 2.2331x; 2.2331x over previous
//
#include <hip/hip_runtime.h>

// Problem constants (from reference)
#define NTRAJ 64
#define TSTEP 64
#define DFEAT 256
#define NT    (NTRAJ * TSTEP)   // 4096
#define MROWS (2 * NT)          // 8192
#define NBLK  256

// Derived mask sums (exact integers):
//   sum(pos_w) = 64 * 128^2 - 8192        = 1,040,384
//   sum(neg_w) = 8192^2 - 64 * 128^2      = 66,060,288
#define POS_DEN 1040384.0
#define NEG_DEN 66060288.0

// Identity: positive_mask = 1 - tm + eye (done cancels: dm carries a tm
// factor, so (1-dm)(1-tm) == (1-tm)). With zn = row-normalized z:
//   pos_sum = sum_g |S_g|^2 - sum_i |zn_i|^2
//   neg_sum = |sum_i zn_i|^2 - sum_g |S_g|^2
// Group g (0..63) rows: [g*64, g*64+64) and [4096+g*64, 4096+g*64+64).
//
// SINGLE kernel, no grid.sync (measured: cooperative sync cost ~30us).
// 256 blocks x 512 threads, 1 block/CU -> all co-resident, spin is safe.
// Producers: block b reduces rows [32b,32b+32) -> P[b][:], Dp[b];
//            __syncthreads (drains vmcnt) -> __threadfence (L2 writeback)
//            -> atomicExch(flags[b],1) (device-scope RMW at coherence point).
// Consumer:  block 255 polls flags with atomicAdd(&f,0) (RMW -> always
//            fresh, immune to per-XCD L2 staleness), acquire-fences, folds
//            the 256 partials deterministically, writes out, resets flags
//            to 0 so each graph replay starts clean. Poison 0xAA != 1, so
//            the very first call is also safe.
__global__ __launch_bounds__(512)
void tsl_onepass_kernel(const float* __restrict__ z,
                        float* __restrict__ P,      // [256][256]
                        float* __restrict__ Dp,     // [256]
                        unsigned* __restrict__ flags, // [256]
                        float* __restrict__ out)    // [2]
{
    const int b    = blockIdx.x;     // 0..255
    const int tid  = threadIdx.x;    // 0..511
    const int w    = tid >> 6;       // wave 0..7
    const int lane = tid & 63;       // 0..63

    __shared__ float  S[8][256];
    __shared__ float  dd[8];
    __shared__ double W[3][4];

    // ---------------- phase 1: per-block partial sum-vector ----------------
    float a0 = 0.f, a1 = 0.f, a2 = 0.f, a3 = 0.f;
    float dpart = 0.f;

    #pragma unroll
    for (int r = 0; r < 4; ++r) {
        const int row = b * 32 + w * 4 + r;
        const float4 v = *reinterpret_cast<const float4*>(
            z + (size_t)row * DFEAT + (size_t)lane * 4);

        float ss = v.x * v.x + v.y * v.y + v.z * v.z + v.w * v.w;
        #pragma unroll
        for (int off = 32; off > 0; off >>= 1)
            ss += __shfl_xor(ss, off, 64);

        const float rinv = 1.0f / fmaxf(sqrtf(ss), 1e-8f);
        a0 += v.x * rinv;
        a1 += v.y * rinv;
        a2 += v.z * rinv;
        a3 += v.w * rinv;
        if (lane == 0) dpart += ss * rinv * rinv;   // |zn_row|^2
    }

    *reinterpret_cast<float4*>(&S[w][lane * 4]) = make_float4(a0, a1, a2, a3);
    if (lane == 0) dd[w] = dpart;
    __syncthreads();

    if (tid < 256) {
        float s = 0.f;
        #pragma unroll
        for (int k = 0; k < 8; ++k) s += S[k][tid];
        P[b * 256 + tid] = s;
        if (tid == 0) {
            float d = 0.f;
            #pragma unroll
            for (int k = 0; k < 8; ++k) d += dd[k];
            Dp[b] = d;
        }
    }

    // publish: barrier drains this block's global stores (vmcnt(0) before
    // s_barrier), then tid0 release-fences (L2 writeback) and sets the flag.
    __syncthreads();
    if (tid == 0) {
        __threadfence();                 // agent-scope: make P/Dp visible
        atomicExch(&flags[b], 1u);       // device-scope RMW
    }

    if (b != NBLK - 1) return;

    // ---------------- consumer: block 255 ----------------
    if (tid < 256) {
        // atomic RMW poll -> reads at coherence point, never stale
        while (atomicAdd(&flags[tid], 0u) != 1u) { /* spin */ }
    }
    __threadfence();                     // acquire: invalidate L1/L2
    __syncthreads();

    if (tid < 256) {
        double g1 = 0.0, col = 0.0;
        #pragma unroll 8
        for (int g = 0; g < 64; ++g) {
            const float s = P[(2 * g) * 256 + tid] + P[(2 * g + 1) * 256 + tid] +
                            P[(128 + 2 * g) * 256 + tid] + P[(129 + 2 * g) * 256 + tid];
            g1  += (double)s * (double)s;
            col += (double)s;
        }
        double g2 = col * col;
        double dg = (double)Dp[tid];

        #pragma unroll
        for (int off = 32; off > 0; off >>= 1) {
            g1 += __shfl_down(g1, off, 64);
            g2 += __shfl_down(g2, off, 64);
            dg += __shfl_down(dg, off, 64);
        }
        if (lane == 0) { W[0][w] = g1; W[1][w] = g2; W[2][w] = dg; }
    }
    __syncthreads();

    if (tid == 0) {
        const double G1 = W[0][0] + W[0][1] + W[0][2] + W[0][3];
        const double G2 = W[1][0] + W[1][1] + W[1][2] + W[1][3];
        const double DG = W[2][0] + W[2][1] + W[2][2] + W[2][3];
        out[0] = (float)((G1 - DG) / POS_DEN);   // positive_sim
        out[1] = (float)((G2 - G1) / NEG_DEN);   // negative_sim
    }

    // reset flags so the next graph replay starts from a clean state
    __syncthreads();
    if (tid < 256) atomicExch(&flags[tid], 0u);
}

extern "C" void kernel_launch(void* const* d_in, const int* in_sizes, int n_in,
                              void* d_out, int out_size, void* d_ws, size_t ws_size,
                              hipStream_t stream) {
    const float* z = (const float*)d_in[0];
    // d_in[1] (done) provably unused: (1-dm)(1-tm) == (1-tm).
    char* ws = (char*)d_ws;
    float*    P     = (float*)ws;                         // 256*256 f32
    float*    Dp    = (float*)(ws + 256 * 256 * 4);       // 256 f32
    unsigned* flags = (unsigned*)(ws + 256 * 256 * 4 + 256 * 4); // 256 u32
    float*    out   = (float*)d_out;

    tsl_onepass_kernel<<<NBLK, 512, 0, stream>>>(z, P, Dp, flags, out);
}

// Round 5
// 15.407 us; speedup vs baseline: 2.9303x; 1.3122x over previous
//
#include <hip/hip_runtime.h>

// Problem constants (from reference)
#define NTRAJ 64
#define TSTEP 64
#define DFEAT 256
#define NT    (NTRAJ * TSTEP)   // 4096
#define MROWS (2 * NT)          // 8192
#define NBLK  256

// Derived mask sums (exact integers):
//   sum(pos_w) = 64 * 128^2 - 8192        = 1,040,384
//   sum(neg_w) = 8192^2 - 64 * 128^2      = 66,060,288
#define POS_DEN 1040384.0
#define NEG_DEN 66060288.0

// Identity: positive_mask = 1 - tm + eye (done cancels: dm carries a tm
// factor, so (1-dm)(1-tm) == (1-tm)). With zn = row-normalized z:
//   pos_sum = sum_g |S_g|^2 - sum_i |zn_i|^2
//   neg_sum = |sum_i zn_i|^2 - sum_g |S_g|^2
// Group g (0..63) rows: [g*64, g*64+64) and [4096+g*64, 4096+g*64+64).
//
// SINGLE kernel, ticket pattern, ZERO spinning, ZERO producer fences:
//  - producers publish partials with device-scope atomicExch (RMWs land at
//    the cross-XCD coherence point; no __threadfence/L2-writeback needed)
//  - __syncthreads() drains vmcnt -> all publishes acked before tid0's
//    ticket atomicAdd
//  - the block whose ticket old value satisfies (old & 255)==255 is the
//    LAST to finish phase 1; it alone acquire-fences (cache invalidate),
//    plain-loads the partials from the coherence point, and folds.
//  - ticket free-runs mod 2^32: garbage init (0xAAAAAAAA poison) and graph
//    replays are both safe — each call consumes exactly 256 increments so
//    exactly one block per call sees old%256==255. Which block folds varies,
//    but the fold order/math is fixed -> deterministic output.
__global__ __launch_bounds__(512)
void tsl_ticket_kernel(const float* __restrict__ z,
                       float* __restrict__ P,        // [256][256]
                       float* __restrict__ Dp,       // [256]
                       unsigned* __restrict__ ticket, // [1]
                       float* __restrict__ out)      // [2]
{
    const int b    = blockIdx.x;     // 0..255
    const int tid  = threadIdx.x;    // 0..511
    const int w    = tid >> 6;       // wave 0..7
    const int lane = tid & 63;       // 0..63

    __shared__ float  S[8][256];
    __shared__ float  dd[8];
    __shared__ double W[3][4];
    __shared__ int    lastFlag;

    // ---------------- phase 1: per-block partial sum-vector ----------------
    float a0 = 0.f, a1 = 0.f, a2 = 0.f, a3 = 0.f;
    float dpart = 0.f;

    #pragma unroll
    for (int r = 0; r < 4; ++r) {
        const int row = b * 32 + w * 4 + r;
        const float4 v = *reinterpret_cast<const float4*>(
            z + (size_t)row * DFEAT + (size_t)lane * 4);

        float ss = v.x * v.x + v.y * v.y + v.z * v.z + v.w * v.w;
        #pragma unroll
        for (int off = 32; off > 0; off >>= 1)
            ss += __shfl_xor(ss, off, 64);

        const float rinv = 1.0f / fmaxf(sqrtf(ss), 1e-8f);
        a0 += v.x * rinv;
        a1 += v.y * rinv;
        a2 += v.z * rinv;
        a3 += v.w * rinv;
        if (lane == 0) dpart += ss * rinv * rinv;   // |zn_row|^2
    }

    *reinterpret_cast<float4*>(&S[w][lane * 4]) = make_float4(a0, a1, a2, a3);
    if (lane == 0) dd[w] = dpart;
    __syncthreads();

    // publish partials via device-scope RMW (coherence point, fence-free)
    if (tid < 256) {
        float s = 0.f;
        #pragma unroll
        for (int k = 0; k < 8; ++k) s += S[k][tid];
        atomicExch(&P[b * 256 + tid], s);
        if (tid == 0) {
            float d = 0.f;
            #pragma unroll
            for (int k = 0; k < 8; ++k) d += dd[k];
            atomicExch(&Dp[b], d);
        }
    }

    // drain: every wave's RMWs are acked (vmcnt 0) before the barrier
    // releases tid0 to take a ticket.
    __syncthreads();
    if (tid == 0) {
        const unsigned old = atomicAdd(ticket, 1u);
        lastFlag = ((old & (NBLK - 1u)) == NBLK - 1u);
    }
    __syncthreads();
    if (!lastFlag) return;

    // ---------------- fold: last-arriving block only ----------------
    __threadfence();   // acquire: invalidate local caches before plain loads
    __syncthreads();

    if (tid < 256) {
        double g1 = 0.0, col = 0.0;
        #pragma unroll 8
        for (int g = 0; g < 64; ++g) {
            const float s = P[(2 * g) * 256 + tid] + P[(2 * g + 1) * 256 + tid] +
                            P[(128 + 2 * g) * 256 + tid] + P[(129 + 2 * g) * 256 + tid];
            g1  += (double)s * (double)s;
            col += (double)s;
        }
        double g2 = col * col;
        double dg = (double)Dp[tid];

        #pragma unroll
        for (int off = 32; off > 0; off >>= 1) {
            g1 += __shfl_down(g1, off, 64);
            g2 += __shfl_down(g2, off, 64);
            dg += __shfl_down(dg, off, 64);
        }
        if (lane == 0) { W[0][w] = g1; W[1][w] = g2; W[2][w] = dg; }
    }
    __syncthreads();

    if (tid == 0) {
        const double G1 = W[0][0] + W[0][1] + W[0][2] + W[0][3];
        const double G2 = W[1][0] + W[1][1] + W[1][2] + W[1][3];
        const double DG = W[2][0] + W[2][1] + W[2][2] + W[2][3];
        out[0] = (float)((G1 - DG) / POS_DEN);   // positive_sim
        out[1] = (float)((G2 - G1) / NEG_DEN);   // negative_sim
    }
}

extern "C" void kernel_launch(void* const* d_in, const int* in_sizes, int n_in,
                              void* d_out, int out_size, void* d_ws, size_t ws_size,
                              hipStream_t stream) {
    const float* z = (const float*)d_in[0];
    // d_in[1] (done) provably unused: (1-dm)(1-tm) == (1-tm).
    char* ws = (char*)d_ws;
    float*    P      = (float*)ws;                           // 256*256 f32
    float*    Dp     = (float*)(ws + 256 * 256 * 4);         // 256 f32
    unsigned* ticket = (unsigned*)(ws + 256 * 256 * 4 + 256 * 4); // 1 u32
    float*    out    = (float*)d_out;

    tsl_ticket_kernel<<<NBLK, 512, 0, stream>>>(z, P, Dp, ticket, out);
}